// Round 1
// baseline (561.950 us; speedup 1.0000x reference)
//
#include <hip/hip_runtime.h>

// ApplyDF: deep-filtering of the first NB_DF complex frequency bins with a
// 5-tap causal complex FIR over time; remaining bins pass through.
//
// spec : (B=32, 1, T=2000, F=481, 2) fp32
// coefs: (B=32, ORDER=5, T=2000, NB_DF=96, 2) fp32
// out  : same shape as spec, fp32
//
// out[b,t,f<96] = sum_{n=0..4} spec[b, t+n-4, f] * coefs[b,n,t,f]   (complex)
//   (taps with t+n-4 < 0 contribute zero — zero padding in the reference)
// out[b,t,f>=96] = spec[b,t,f]
//
// Memory-bound: ~738 MB compulsory traffic, ~184 MFLOP. One block per (b,t),
// thread f owns one complex bin; everything is coalesced float2.

constexpr int ORDER = 5;
constexpr int NB_DF = 96;
constexpr int T_DIM = 2000;
constexpr int F_DIM = 481;
constexpr int B_DIM = 32;

__global__ __launch_bounds__(512) void ApplyDF_29231547416739_kernel(
    const float2* __restrict__ spec,
    const float2* __restrict__ coefs,
    float2* __restrict__ out)
{
    const int t = blockIdx.x;
    const int b = blockIdx.y;
    const int f = threadIdx.x;
    if (f >= F_DIM) return;

    const size_t row = ((size_t)b * T_DIM + t) * F_DIM;

    if (f < NB_DF) {
        float2 acc = make_float2(0.0f, 0.0f);
#pragma unroll
        for (int n = 0; n < ORDER; ++n) {
            const int tt = t + n - (ORDER - 1);  // pad_before = ORDER-1-LOOKAHEAD = 4
            if (tt >= 0) {
                const float2 s = spec[((size_t)b * T_DIM + tt) * F_DIM + f];
                const float2 c = coefs[(((size_t)b * ORDER + n) * T_DIM + t) * NB_DF + f];
                acc.x += s.x * c.x - s.y * c.y;   // real
                acc.y += s.x * c.y + s.y * c.x;   // imag
            }
        }
        out[row + f] = acc;
    } else {
        out[row + f] = spec[row + f];
    }
}

extern "C" void kernel_launch(void* const* d_in, const int* in_sizes, int n_in,
                              void* d_out, int out_size, void* d_ws, size_t ws_size,
                              hipStream_t stream) {
    const float2* spec  = (const float2*)d_in[0];
    const float2* coefs = (const float2*)d_in[1];
    float2* out = (float2*)d_out;

    dim3 grid(T_DIM, B_DIM);
    dim3 block(512);
    ApplyDF_29231547416739_kernel<<<grid, block, 0, stream>>>(spec, coefs, out);
}